// Round 17
// baseline (522.283 us; speedup 1.0000x reference)
//
#include <hip/hip_runtime.h>
#include <math.h>

#define C_CAP 1000000
#define DIM 64

// ws layout (floats)
#define SCORES_OFF 0          // [1,000,000] scores
#define P1_OFF     1000000    // per-block pairs {m, l}, stride 4, NB1 blocks
#define HDR_OFF    1010000    // [0]=M, [1]=L_shift, [2]=argmax (int bits)
#define ACC_OFF    1010064    // [64] atomic accumulator
#define PROBE_OFF  1010192    // [8192] probe sink (never read; DCE keep-alive)

#define NB1 1024              // K1 grid: 4 blocks/CU at 16 waves/CU (R3 config)
#define NW1 (NB1 * 4)
#define NTILES (C_CAP / 16)   // 62500: 16 rows (4 KB) per wave-iteration in K1
#define NB3 2048
#define NW3 (NB3 * 4)
#define NCHUNKS (C_CAP / 64)  // 15625

#define NBP 2048              // probe grid: 8 blocks/CU (R9 probe config)
#define NWP (NBP * 4)

// DPP row_shr sum step: x += (lane's row-position >= n ? x[lane-n] : 0) within
// each 16-lane row. VALU pipe (v_mov_dpp + v_add), ~4 cyc/step -- replaces the
// ds_swizzle (~120 cyc latency, DS pipe) that __shfl_xor emits.
// ROW_SHR n = 0x110 | n. CTRL must be a compile-time constant -> template arg
// (R16 compile error: __builtin_amdgcn_update_dpp rejects runtime ctrl).
template <int CTRL>
__device__ __forceinline__ float dpp_shr_add(float x)
{
    int s = __builtin_amdgcn_update_dpp(0, __float_as_int(x),
                                        CTRL, 0xf, 0xf, true);
    return x + __int_as_float(s);
}

// ---------------------------------------------------------------------------
// K1: scores with DPP reduction. UNCONFOUNDED A/B vs R3's K1: identical
// contiguous 4-KB-tile loads (the pattern the R9 probe proved runs 6.9 TB/s),
// identical grid/launch_bounds/expf-count/store-volume -- ONLY the 16-lane
// dot reduction changes: __shfl_xor butterfly (16 DS ops/tile, 4-deep
// dependent chains) -> 16 DPP row_shr adds (VALU, ~4cyc each).
// After the 4-step shr chain, lane cl==15 of each g-group holds the full
// row-sums s0..s3 (rows 16t+4j+g). That lane accumulates l/m and stores the
// 4 scores (4 masked stores, 4 active lanes each: t*16+4j+g for g=0..3).
// l accumulates UNSHIFTED sum(exp(s)) (max ~42 -> <=1e20, fp32-safe).
// ---------------------------------------------------------------------------
__global__ __launch_bounds__(256, 4) void nd_scores(
    const float* __restrict__ query,
    const float* __restrict__ keys,
    float* __restrict__ ws, int ntiles, int stride)
{
    const int tid  = threadIdx.x;
    const int lane = tid & 63;
    const int wave = tid >> 6;
    const int cl   = lane & 15;
    const int g    = lane >> 4;
    const int wglobal = blockIdx.x * 4 + wave;

    const float4 q4 = ((const float4*)query)[cl];
    const float4* __restrict__ k4p = (const float4*)keys;

    float m = -1e30f, l = 0.f;

    for (int t = wglobal; t < ntiles; t += stride) {
        const float4* __restrict__ kp = k4p + (size_t)t * 256 + lane;
        const float4 k0 = kp[0];
        const float4 k1 = kp[64];
        const float4 k2 = kp[128];
        const float4 k3 = kp[192];

        float s0 = fmaf(k0.x, q4.x, fmaf(k0.y, q4.y, fmaf(k0.z, q4.z, k0.w * q4.w)));
        float s1 = fmaf(k1.x, q4.x, fmaf(k1.y, q4.y, fmaf(k1.z, q4.z, k1.w * q4.w)));
        float s2 = fmaf(k2.x, q4.x, fmaf(k2.y, q4.y, fmaf(k2.z, q4.z, k2.w * q4.w)));
        float s3 = fmaf(k3.x, q4.x, fmaf(k3.y, q4.y, fmaf(k3.z, q4.z, k3.w * q4.w)));

        // 4 interleaved 4-step DPP shr chains (VALU, no DS)
        s0 = dpp_shr_add<0x111>(s0); s1 = dpp_shr_add<0x111>(s1);
        s2 = dpp_shr_add<0x111>(s2); s3 = dpp_shr_add<0x111>(s3);
        s0 = dpp_shr_add<0x112>(s0); s1 = dpp_shr_add<0x112>(s1);
        s2 = dpp_shr_add<0x112>(s2); s3 = dpp_shr_add<0x112>(s3);
        s0 = dpp_shr_add<0x114>(s0); s1 = dpp_shr_add<0x114>(s1);
        s2 = dpp_shr_add<0x114>(s2); s3 = dpp_shr_add<0x114>(s3);
        s0 = dpp_shr_add<0x118>(s0); s1 = dpp_shr_add<0x118>(s1);
        s2 = dpp_shr_add<0x118>(s2); s3 = dpp_shr_add<0x118>(s3);

        const bool hot = (cl == 15);   // lane 15 of each row holds the sums
        const float e = (__expf(s0) + __expf(s1)) + (__expf(s2) + __expf(s3));
        l += hot ? e : 0.f;
        const float s_mx = fmaxf(fmaxf(s0, s1), fmaxf(s2, s3));
        m = hot ? fmaxf(m, s_mx) : m;

        if (hot) {
            float* sp = ws + SCORES_OFF + t * 16 + g;
            sp[0]  = s0;   // row 16t + 0 + g
            sp[4]  = s1;   // row 16t + 4 + g
            sp[8]  = s2;   // row 16t + 8 + g
            sp[12] = s3;   // row 16t + 12 + g
        }
    }

    // end-of-kernel combine (non-hot lanes carry l=0, m=-1e30)
    #pragma unroll
    for (int off = 1; off <= 32; off <<= 1) {
        l += __shfl_xor(l, off);
        m = fmaxf(m, __shfl_xor(m, off));
    }

    __shared__ float s_m[4], s_l[4];
    if (lane == 0) { s_m[wave] = m; s_l[wave] = l; }
    __syncthreads();
    if (tid == 0) {
        float bm = s_m[0], bl = s_l[0];
        #pragma unroll
        for (int wv = 1; wv < 4; ++wv) {
            bl += s_l[wv];
            bm = fmaxf(bm, s_m[wv]);
        }
        float* bp = ws + P1_OFF + (size_t)blockIdx.x * 4;
        bp[0] = bm;
        bp[1] = bl;
    }
}

// ---------------------------------------------------------------------------
// K2: single block. Reduce per-block pairs -> M, L_shift; zero ACC. (R3)
// ---------------------------------------------------------------------------
__global__ __launch_bounds__(256) void nd_reduce(float* __restrict__ ws, int nb)
{
    const int tid = threadIdx.x;
    float m = -1e30f, l = 0.f;
    for (int b = tid; b < nb; b += 256) {
        const float* bp = ws + P1_OFF + (size_t)b * 4;
        l += bp[1];
        m = fmaxf(m, bp[0]);
    }
    __shared__ float sm[256], sl[256];
    sm[tid] = m; sl[tid] = l;
    __syncthreads();
    for (int s = 128; s > 0; s >>= 1) {
        if (tid < s) {
            sl[tid] += sl[tid + s];
            sm[tid] = fmaxf(sm[tid], sm[tid + s]);
        }
        __syncthreads();
    }
    if (tid == 0) {
        const float M = sm[0];
        ws[HDR_OFF + 0] = M;
        ws[HDR_OFF + 1] = sl[0] * __expf(-M);
        ((int*)ws)[HDR_OFF + 2] = 0;
    }
    if (tid < 64) ws[ACC_OFF + tid] = 0.f;
}

// ---------------------------------------------------------------------------
// K3: selective P.V + argmax via s == M bit-equality. (R3, unchanged)
// ---------------------------------------------------------------------------
__global__ __launch_bounds__(256, 8) void nd_pv(
    const float* __restrict__ values,
    float* __restrict__ ws, int nchunks, int nwaves_total)
{
    const int tid  = threadIdx.x;
    const int lane = tid & 63;
    const int wave = tid >> 6;
    const int wglobal = blockIdx.x * 4 + wave;

    const float M   = ws[HDR_OFF];
    const float thr = M - 23.0f;
    float acc = 0.f;

    for (int c = wglobal; c < nchunks; c += nwaves_total) {
        const float s = ws[SCORES_OFF + (size_t)c * 64 + lane];
        unsigned long long mask = __ballot(s > thr);
        if (mask) {
            if (s == M) ((int*)ws)[HDR_OFF + 2] = c * 64 + lane;
            const float w = __expf(s - M);
            while (mask) {
                const int b = __ffsll((long long)mask) - 1;
                mask &= mask - 1;
                const float wb = __shfl(w, b);
                acc = fmaf(wb, values[(size_t)(c * 64 + b) * 64 + lane], acc);
            }
        }
    }

    __shared__ float sA[4][64];
    sA[wave][lane] = acc;
    __syncthreads();
    if (tid < 64) {
        const float v = sA[0][tid] + sA[1][tid] + sA[2][tid] + sA[3][tid];
        if (v != 0.f) atomicAdd(ws + ACC_OFF + tid, v);
    }
}

// ---------------------------------------------------------------------------
// K4: finalize. (R3, unchanged)
// ---------------------------------------------------------------------------
__global__ __launch_bounds__(128) void nd_final(
    const float* __restrict__ ws, float* __restrict__ out)
{
    const int tid = threadIdx.x;
    if (tid < 64) out[tid] = ws[ACC_OFF + tid] / ws[HDR_OFF + 1];
    if (tid == 64) out[64] = (float)((const int*)ws)[HDR_OFF + 2];
}

// ---------------------------------------------------------------------------
// P_exp8: the R9 pure-load probe + 8 __expf per 4-KB tile. Disambiguates
// whether expf (held constant in every K1 variant) is secretly expensive.
// expf free  -> ~40 us appendix. expf guilty -> ~200 us appendix.
// Inputs |k| <= ~6 -> exp finite. One live store per wave (DCE keep-alive).
// ---------------------------------------------------------------------------
__global__ __launch_bounds__(256, 8) void nd_probe_exp(
    const float* __restrict__ keys,
    float* __restrict__ ws)
{
    const int tid  = threadIdx.x;
    const int lane = tid & 63;
    const int wave = tid >> 6;
    const int wglobal = blockIdx.x * 4 + wave;

    const float4* __restrict__ k4p = (const float4*)keys;

    float a = 0.f;
    for (int t = wglobal; t < NTILES; t += NWP) {
        const float4* __restrict__ kp = k4p + (size_t)t * 256 + lane;
        const float4 k0 = kp[0];
        const float4 k1 = kp[64];
        const float4 k2 = kp[128];
        const float4 k3 = kp[192];
        a += (__expf(k0.x) + __expf(k0.y)) + (__expf(k0.z) + __expf(k0.w));
        a += (__expf(k1.x) + __expf(k1.y)) + (__expf(k1.z) + __expf(k1.w));
        a += (k2.x + k2.y) + (k2.z + k2.w);
        a += (k3.x + k3.y) + (k3.z + k3.w);
    }
    if (lane == 0) ws[PROBE_OFF + wglobal] = a;   // live sink, never read
}

extern "C" void kernel_launch(void* const* d_in, const int* in_sizes, int n_in,
                              void* d_out, int out_size, void* d_ws, size_t ws_size,
                              hipStream_t stream) {
    const float* query  = (const float*)d_in[0];
    const float* keys   = (const float*)d_in[1];
    const float* values = (const float*)d_in[2];
    float* out = (float*)d_out;
    float* ws  = (float*)d_ws;

    nd_scores<<<NB1, 256, 0, stream>>>(query, keys, ws, NTILES, NW1);
    nd_reduce<<<1, 256, 0, stream>>>(ws, NB1);
    nd_pv<<<NB3, 256, 0, stream>>>(values, ws, NCHUNKS, NW3);
    nd_final<<<1, 128, 0, stream>>>(ws, out);
    nd_probe_exp<<<NBP, 256, 0, stream>>>(keys, ws);   // diagnostic appendix
}

// Round 19
// 459.049 us; speedup vs baseline: 1.1377x; 1.1377x over previous
//
#include <hip/hip_runtime.h>
#include <math.h>

#define C_CAP 1000000
#define DIM 64

// ws layout (floats)
#define SCORES_OFF 0          // [1,000,000] scores
#define P1_OFF     1000000    // per-block pairs {m, l}, stride 4, NB1 blocks
#define HDR_OFF    1010000    // [0]=M, [1]=L_shift, [2]=argmax (int bits)
#define ACC_OFF    1010064    // [64] atomic accumulator

#define NB1 1024              // K1 grid: 4 blocks/CU at 16 waves/CU
#define NW1 (NB1 * 4)
#define NTILES (C_CAP / 16)   // 62500: 16 rows per wave-iteration in K1
#define NB3 2048
#define NW3 (NB3 * 4)
#define NCHUNKS (C_CAP / 64)  // 15625

// ext_vector float4 so __builtin_nontemporal_load accepts it (struct float4
// is rejected; clang vector types are supported and emit global_load_dwordx4
// with the nt cache hint).
typedef float f4 __attribute__((ext_vector_type(4)));

// ---------------------------------------------------------------------------
// K1: EXACT R3 structure (measured-best 481.3 us total, twice), with ONE
// change: key loads are NON-TEMPORAL. Rationale (R17 post-mortem): five
// structurally different K1s all pin at ~105 us = 2.5 TB/s cold-read, while
// the same load pattern runs 6.9 TB/s L3-warm (R9 probe -- which was
// confounded: it ran last, after K1 had just made keys L3-resident; the
// 250 MiB keys array fits the 256 MiB Infinity Cache). Working theory:
// cold reads are cache-miss-handling bound. Keys have zero reuse in this
// pipeline, so nt (bypass L2/L3 allocation) is semantically free; if the
// throttle includes fill/allocation overhead it lifts, if pure MSHR/latency
// it's null and we are at the cold-read roofline.
// ---------------------------------------------------------------------------
__global__ __launch_bounds__(256, 4) void nd_scores(
    const float* __restrict__ query,
    const float* __restrict__ keys,
    float* __restrict__ ws, int ntiles, int stride)
{
    const int tid  = threadIdx.x;
    const int lane = tid & 63;
    const int wave = tid >> 6;
    const int cl   = lane & 15;
    const int g    = lane >> 4;
    const int wglobal = blockIdx.x * 4 + wave;

    const float4 q4 = ((const float4*)query)[cl];
    const f4* __restrict__ k4p = (const f4*)keys;

    float m = -1e30f, l = 0.f;

    f4 A0, A1, A2, A3;   // current tile
    f4 B0, B1, B2, B3;   // prefetch tile

#define LOADK(b0, b1, b2, b3, tt) {                                        \
        const f4* __restrict__ kp = k4p + (size_t)(tt) * 256 + lane;       \
        b0 = __builtin_nontemporal_load(kp);                               \
        b1 = __builtin_nontemporal_load(kp + 64);                          \
        b2 = __builtin_nontemporal_load(kp + 128);                         \
        b3 = __builtin_nontemporal_load(kp + 192);                         \
    }

#define COMPUTE(b0, b1, b2, b3, tt) {                                          \
        float s0 = fmaf(b0.x, q4.x, fmaf(b0.y, q4.y, fmaf(b0.z, q4.z, b0.w * q4.w))); \
        float s1 = fmaf(b1.x, q4.x, fmaf(b1.y, q4.y, fmaf(b1.z, q4.z, b1.w * q4.w))); \
        float s2 = fmaf(b2.x, q4.x, fmaf(b2.y, q4.y, fmaf(b2.z, q4.z, b2.w * q4.w))); \
        float s3 = fmaf(b3.x, q4.x, fmaf(b3.y, q4.y, fmaf(b3.z, q4.z, b3.w * q4.w))); \
        s0 += __shfl_xor(s0, 1); s1 += __shfl_xor(s1, 1);                      \
        s2 += __shfl_xor(s2, 1); s3 += __shfl_xor(s3, 1);                      \
        s0 += __shfl_xor(s0, 2); s1 += __shfl_xor(s1, 2);                      \
        s2 += __shfl_xor(s2, 2); s3 += __shfl_xor(s3, 2);                      \
        s0 += __shfl_xor(s0, 4); s1 += __shfl_xor(s1, 4);                      \
        s2 += __shfl_xor(s2, 4); s3 += __shfl_xor(s3, 4);                      \
        s0 += __shfl_xor(s0, 8); s1 += __shfl_xor(s1, 8);                      \
        s2 += __shfl_xor(s2, 8); s3 += __shfl_xor(s3, 8);                      \
        const float sv = (cl == 0) ? s0 : (cl == 1) ? s1 : (cl == 2) ? s2 : s3; \
        if (cl < 4) ws[SCORES_OFF + (tt) * 16 + 4 * cl + g] = sv;              \
        l += (__expf(s0) + __expf(s1)) + (__expf(s2) + __expf(s3));            \
        m = fmaxf(m, fmaxf(fmaxf(s0, s1), fmaxf(s2, s3)));                     \
    }

    int t = wglobal;                 // wglobal < 4096 <= ntiles: always valid
    LOADK(A0, A1, A2, A3, t);
    while (true) {
        const int tn = t + stride;
        if (tn < ntiles) LOADK(B0, B1, B2, B3, tn);
        COMPUTE(A0, A1, A2, A3, t);
        if (tn >= ntiles) break;
        t = tn + stride;
        if (t < ntiles) LOADK(A0, A1, A2, A3, t);
        COMPUTE(B0, B1, B2, B3, tn);
        if (t >= ntiles) break;
    }

#undef LOADK
#undef COMPUTE

    l += __shfl_xor(l, 16); m = fmaxf(m, __shfl_xor(m, 16));
    l += __shfl_xor(l, 32); m = fmaxf(m, __shfl_xor(m, 32));

    __shared__ float s_m[4], s_l[4];
    if (lane == 0) { s_m[wave] = m; s_l[wave] = l; }
    __syncthreads();
    if (tid == 0) {
        float bm = s_m[0], bl = s_l[0];
        #pragma unroll
        for (int wv = 1; wv < 4; ++wv) {
            bl += s_l[wv];
            bm = fmaxf(bm, s_m[wv]);
        }
        float* bp = ws + P1_OFF + (size_t)blockIdx.x * 4;
        bp[0] = bm;
        bp[1] = bl;
    }
}

// ---------------------------------------------------------------------------
// K2: single block. Reduce per-block pairs -> M, L_shift; zero ACC. (R3)
// ---------------------------------------------------------------------------
__global__ __launch_bounds__(256) void nd_reduce(float* __restrict__ ws, int nb)
{
    const int tid = threadIdx.x;
    float m = -1e30f, l = 0.f;
    for (int b = tid; b < nb; b += 256) {
        const float* bp = ws + P1_OFF + (size_t)b * 4;
        l += bp[1];
        m = fmaxf(m, bp[0]);
    }
    __shared__ float sm[256], sl[256];
    sm[tid] = m; sl[tid] = l;
    __syncthreads();
    for (int s = 128; s > 0; s >>= 1) {
        if (tid < s) {
            sl[tid] += sl[tid + s];
            sm[tid] = fmaxf(sm[tid], sm[tid + s]);
        }
        __syncthreads();
    }
    if (tid == 0) {
        const float M = sm[0];
        ws[HDR_OFF + 0] = M;
        ws[HDR_OFF + 1] = sl[0] * __expf(-M);   // L_shift = sum(exp(s-M))
        ((int*)ws)[HDR_OFF + 2] = 0;
    }
    if (tid < 64) ws[ACC_OFF + tid] = 0.f;
}

// ---------------------------------------------------------------------------
// K3: selective P.V + argmax via s == M bit-equality. (R3, unchanged)
// ---------------------------------------------------------------------------
__global__ __launch_bounds__(256, 8) void nd_pv(
    const float* __restrict__ values,
    float* __restrict__ ws, int nchunks, int nwaves_total)
{
    const int tid  = threadIdx.x;
    const int lane = tid & 63;
    const int wave = tid >> 6;
    const int wglobal = blockIdx.x * 4 + wave;

    const float M   = ws[HDR_OFF];
    const float thr = M - 23.0f;
    float acc = 0.f;

    for (int c = wglobal; c < nchunks; c += nwaves_total) {
        const float s = ws[SCORES_OFF + (size_t)c * 64 + lane];
        unsigned long long mask = __ballot(s > thr);
        if (mask) {
            if (s == M) ((int*)ws)[HDR_OFF + 2] = c * 64 + lane;
            const float w = __expf(s - M);
            while (mask) {
                const int b = __ffsll((long long)mask) - 1;
                mask &= mask - 1;
                const float wb = __shfl(w, b);
                acc = fmaf(wb, values[(size_t)(c * 64 + b) * 64 + lane], acc);
            }
        }
    }

    __shared__ float sA[4][64];
    sA[wave][lane] = acc;
    __syncthreads();
    if (tid < 64) {
        const float v = sA[0][tid] + sA[1][tid] + sA[2][tid] + sA[3][tid];
        if (v != 0.f) atomicAdd(ws + ACC_OFF + tid, v);
    }
}

// ---------------------------------------------------------------------------
// K4: finalize. (R3, unchanged)
// ---------------------------------------------------------------------------
__global__ __launch_bounds__(128) void nd_final(
    const float* __restrict__ ws, float* __restrict__ out)
{
    const int tid = threadIdx.x;
    if (tid < 64) out[tid] = ws[ACC_OFF + tid] / ws[HDR_OFF + 1];
    if (tid == 64) out[64] = (float)((const int*)ws)[HDR_OFF + 2];
}

extern "C" void kernel_launch(void* const* d_in, const int* in_sizes, int n_in,
                              void* d_out, int out_size, void* d_ws, size_t ws_size,
                              hipStream_t stream) {
    const float* query  = (const float*)d_in[0];
    const float* keys   = (const float*)d_in[1];
    const float* values = (const float*)d_in[2];
    float* out = (float*)d_out;
    float* ws  = (float*)d_ws;

    nd_scores<<<NB1, 256, 0, stream>>>(query, keys, ws, NTILES, NW1);
    nd_reduce<<<1, 256, 0, stream>>>(ws, NB1);
    nd_pv<<<NB3, 256, 0, stream>>>(values, ws, NCHUNKS, NW3);
    nd_final<<<1, 128, 0, stream>>>(ws, out);
}